// Round 8
// baseline (214.071 us; speedup 1.0000x reference)
//
#include <hip/hip_runtime.h>

#define D_DIM 1024
#define NF 513            // rfft bins = D/2+1
#define NB 4              // batch
#define NS 2048           // sequence
#define NTOK (NB * NS)    // 8192 tokens
#define NCH 32            // cumsum chunks
#define CHS (NS / NCH)    // 64 steps per chunk

typedef __attribute__((ext_vector_type(8))) short short8_t;   // 8 bf16 = 4 VGPRs
typedef __attribute__((ext_vector_type(4))) float f32x4;

__device__ inline unsigned short f2bf(float f) {
    unsigned u = __builtin_bit_cast(unsigned, f);
    u += 0x7FFFu + ((u >> 16) & 1u);   // round-to-nearest-even
    return (unsigned short)(u >> 16);
}
__device__ inline float bf2f(unsigned short h) {
    unsigned u = ((unsigned)h) << 16;
    return __builtin_bit_cast(float, u);
}
__device__ inline unsigned pkc(float re, float im) {   // packed bf16 complex
    return (unsigned)f2bf(re) | ((unsigned)f2bf(im) << 16);
}
__device__ inline float2 upc(unsigned u) {
    return make_float2(bf2f((unsigned short)(u & 0xFFFFu)), bf2f((unsigned short)(u >> 16)));
}

__global__ __launch_bounds__(256) void convert_x(const float* __restrict__ src,
                                                 unsigned short* __restrict__ dst,
                                                 int n4) {
    int i = blockIdx.x * 256 + threadIdx.x;
    int stride = gridDim.x * 256;
    for (; i < n4; i += stride) {
        float4 v = reinterpret_cast<const float4*>(src)[i];
        ushort4 o;
        o.x = f2bf(v.x); o.y = f2bf(v.y); o.z = f2bf(v.z); o.w = f2bf(v.w);
        reinterpret_cast<ushort4*>(dst)[i] = o;
    }
}

// all four weights in one dispatch: gridDim.y selects the weight
__global__ __launch_bounds__(256) void convert_w(const float* __restrict__ Wq,
                                                 const float* __restrict__ Wk,
                                                 const float* __restrict__ Wv,
                                                 const float* __restrict__ Wo,
                                                 unsigned short* __restrict__ Wqkv,
                                                 unsigned short* __restrict__ Wob) {
    int y = blockIdx.y;
    const float* src = (y == 0) ? Wq : (y == 1) ? Wk : (y == 2) ? Wv : Wo;
    unsigned short* dst = (y < 3) ? (Wqkv + (size_t)y * 1048576) : Wob;
    int i = blockIdx.x * 256 + threadIdx.x;
    float4 v = reinterpret_cast<const float4*>(src)[i];
    ushort4 o;
    o.x = f2bf(v.x); o.y = f2bf(v.y); o.z = f2bf(v.z); o.w = f2bf(v.w);
    reinterpret_cast<ushort4*>(dst)[i] = o;
}

#define BK 32

__device__ inline void gload_lds16(const void* g, void* l) {
    __builtin_amdgcn_global_load_lds(
        (const __attribute__((address_space(1))) void*)g,
        (__attribute__((address_space(3))) void*)l,
        16, 0, 0);
}

// ---------------------------------------------------------------------------
// QKV GEMM: block 256x128, 4 waves, per-wave 128x64 (8x4 fragments).
// Intensity 42.7 FLOP/LDS-byte (vs 32 at 64x64).  2-buffer LDS (48 KB),
// counted vmcnt (6 steady / 0 tail), raw barriers, bank swizzle as R7.
// ---------------------------------------------------------------------------
__global__ __launch_bounds__(256) void gemm_bf16_nt_big(const unsigned short* __restrict__ A,
                                                        const unsigned short* __restrict__ B,
                                                        unsigned short* __restrict__ C,
                                                        int M, int N, int K) {
    __shared__ __attribute__((aligned(16))) unsigned short ldsA[2 * 256 * BK];  // 32 KiB
    __shared__ __attribute__((aligned(16))) unsigned short ldsB[2 * 128 * BK];  // 16 KiB
    const int tid  = threadIdx.x;
    const int wave = tid >> 6;
    const int lane = tid & 63;
    const int l15  = lane & 15;
    const int k8   = (((lane >> 4) ^ ((l15 >> 1) & 3)) << 3);   // read-side swizzled slot
    const int wm   = (wave >> 1) * 128;
    const int wn   = (wave & 1) * 64;
    const int bm   = blockIdx.x * 256;
    const int bn   = blockIdx.y * 128;
    const int crow = tid >> 2;
    const int ccol = (((tid & 3) ^ ((tid >> 3) & 3)) << 3);     // write-side inverse swizzle (global src)
    const int NT   = K / BK;

    const unsigned short* Arow = A + (size_t)(bm + crow) * K + ccol;
    const unsigned short* Brow = B + (size_t)(bn + crow) * K + ccol;
    const size_t rstep = (size_t)64 * K;

    f32x4 acc[8][4];
#pragma unroll
    for (int i = 0; i < 8; ++i)
#pragma unroll
        for (int j = 0; j < 4; ++j)
            acc[i][j] = (f32x4){0.f, 0.f, 0.f, 0.f};

    // STAGE(tile t -> buffer b): 6 global_load_lds per thread (A:4, B:2)
    auto STAGE = [&](int t, int b) {
        const int k0 = t * BK;
        unsigned short* la = &ldsA[b * (256 * BK) + (tid >> 2) * BK + ((tid & 3) << 3)];
        unsigned short* lb = &ldsB[b * (128 * BK) + (tid >> 2) * BK + ((tid & 3) << 3)];
        gload_lds16(Arow + k0,             la);
        gload_lds16(Arow + rstep + k0,     la + 64 * BK);
        gload_lds16(Arow + 2 * rstep + k0, la + 128 * BK);
        gload_lds16(Arow + 3 * rstep + k0, la + 192 * BK);
        gload_lds16(Brow + k0,             lb);
        gload_lds16(Brow + rstep + k0,     lb + 64 * BK);
    };

    STAGE(0, 0);

    for (int j = 0; j < NT; ++j) {
        const int buf = j & 1;
        if (j + 1 < NT) {
            STAGE(j + 1, buf ^ 1);
            asm volatile("s_waitcnt vmcnt(6)" ::: "memory");   // tile j landed; j+1 in flight
        } else {
            asm volatile("s_waitcnt vmcnt(0)" ::: "memory");
        }
        __builtin_amdgcn_s_barrier();
        asm volatile("" ::: "memory");

        const unsigned short* la = &ldsA[buf * (256 * BK)];
        const unsigned short* lb = &ldsB[buf * (128 * BK)];
        short8_t af[8], bfv[4];
#pragma unroll
        for (int mi = 0; mi < 8; ++mi)
            af[mi] = *reinterpret_cast<const short8_t*>(&la[(wm + mi * 16 + l15) * BK + k8]);
#pragma unroll
        for (int ni = 0; ni < 4; ++ni)
            bfv[ni] = *reinterpret_cast<const short8_t*>(&lb[(wn + ni * 16 + l15) * BK + k8]);

        __builtin_amdgcn_s_setprio(1);
#pragma unroll
        for (int mi = 0; mi < 8; ++mi)
#pragma unroll
            for (int ni = 0; ni < 4; ++ni)
                acc[mi][ni] = __builtin_amdgcn_mfma_f32_16x16x32_bf16(af[mi], bfv[ni], acc[mi][ni], 0, 0, 0);
        __builtin_amdgcn_s_setprio(0);

        __builtin_amdgcn_s_barrier();
        asm volatile("" ::: "memory");
    }

#pragma unroll
    for (int mi = 0; mi < 8; ++mi) {
        int rbase = bm + wm + mi * 16 + (lane >> 4) * 4;
#pragma unroll
        for (int ni = 0; ni < 4; ++ni) {
            int col = bn + wn + ni * 16 + l15;
#pragma unroll
            for (int j = 0; j < 4; ++j)
                C[(size_t)(rbase + j) * N + col] = f2bf(acc[mi][ni][j]);
        }
    }
}

// ---------------------------------------------------------------------------
// Out GEMM (proven R7 kernel): 128x128, 4 waves of 64x64, 3-buffer, vmcnt 8/4/0.
// ---------------------------------------------------------------------------
#define BM 128
#define BN 128

template <typename OutT>
__global__ __launch_bounds__(256) void gemm_bf16_nt(const unsigned short* __restrict__ A,
                                                    const unsigned short* __restrict__ B,
                                                    OutT* __restrict__ C,
                                                    int M, int N, int K) {
    __shared__ __attribute__((aligned(16))) unsigned short ldsA[3 * BM * BK];
    __shared__ __attribute__((aligned(16))) unsigned short ldsB[3 * BM * BK];
    const int tid  = threadIdx.x;
    const int wave = tid >> 6;
    const int lane = tid & 63;
    const int l15  = lane & 15;
    const int k8   = (((lane >> 4) ^ ((l15 >> 1) & 3)) << 3);
    const int wm   = (wave >> 1) * 64;
    const int wn   = (wave & 1) * 64;
    const int bm   = blockIdx.x * BM;
    const int bn   = blockIdx.y * BN;
    const int crow = tid >> 2;
    const int ccol = (((tid & 3) ^ ((tid >> 3) & 3)) << 3);
    const int NT   = K / BK;

    const unsigned short* Arow = A + (size_t)(bm + crow) * K + ccol;
    const unsigned short* Brow = B + (size_t)(bn + crow) * K + ccol;
    const size_t rstep = (size_t)64 * K;

    f32x4 acc[4][4];
#pragma unroll
    for (int i = 0; i < 4; ++i)
#pragma unroll
        for (int j = 0; j < 4; ++j)
            acc[i][j] = (f32x4){0.f, 0.f, 0.f, 0.f};

    auto STAGE = [&](int t, int b) {
        const int k0 = t * BK;
        unsigned short* la = &ldsA[b * (BM * BK) + (tid >> 2) * BK + ((tid & 3) << 3)];
        unsigned short* lb = &ldsB[b * (BM * BK) + (tid >> 2) * BK + ((tid & 3) << 3)];
        gload_lds16(Arow + k0, la);
        gload_lds16(Brow + k0, lb);
        gload_lds16(Arow + rstep + k0, la + 64 * BK);
        gload_lds16(Brow + rstep + k0, lb + 64 * BK);
    };

    STAGE(0, 0);
    STAGE(1, 1);

    for (int j = 0; j < NT; ++j) {
        const int buf = j % 3;
        if (j + 2 < NT) STAGE(j + 2, (j + 2) % 3);

        if (j + 2 < NT)      asm volatile("s_waitcnt vmcnt(8)" ::: "memory");
        else if (j + 1 < NT) asm volatile("s_waitcnt vmcnt(4)" ::: "memory");
        else                 asm volatile("s_waitcnt vmcnt(0)" ::: "memory");
        __builtin_amdgcn_s_barrier();
        asm volatile("" ::: "memory");

        const unsigned short* la = &ldsA[buf * (BM * BK)];
        const unsigned short* lb = &ldsB[buf * (BM * BK)];
        short8_t af[4], bfv[4];
#pragma unroll
        for (int mi = 0; mi < 4; ++mi)
            af[mi] = *reinterpret_cast<const short8_t*>(&la[(wm + mi * 16 + l15) * BK + k8]);
#pragma unroll
        for (int ni = 0; ni < 4; ++ni)
            bfv[ni] = *reinterpret_cast<const short8_t*>(&lb[(wn + ni * 16 + l15) * BK + k8]);

        __builtin_amdgcn_s_setprio(1);
#pragma unroll
        for (int mi = 0; mi < 4; ++mi)
#pragma unroll
            for (int ni = 0; ni < 4; ++ni)
                acc[mi][ni] = __builtin_amdgcn_mfma_f32_16x16x32_bf16(af[mi], bfv[ni], acc[mi][ni], 0, 0, 0);
        __builtin_amdgcn_s_setprio(0);

        __builtin_amdgcn_s_barrier();
        asm volatile("" ::: "memory");
    }

#pragma unroll
    for (int mi = 0; mi < 4; ++mi) {
        int rbase = bm + wm + mi * 16 + (lane >> 4) * 4;
#pragma unroll
        for (int ni = 0; ni < 4; ++ni) {
            int col = bn + wn + ni * 16 + l15;
#pragma unroll
            for (int j = 0; j < 4; ++j) {
                float v = acc[mi][ni][j];
                if constexpr (sizeof(OutT) == 4)
                    C[(size_t)(rbase + j) * N + col] = v;
                else
                    C[(size_t)(rbase + j) * N + col] = f2bf(v);
            }
        }
    }
}

// ---------------------------------------------------------------------------
// Radix-4 1024-pt complex FFT in LDS, float2 elements, XOR bank swizzle.
// ---------------------------------------------------------------------------
__device__ inline int sw(int i) { return i ^ ((i >> 4) & 15); }

__device__ inline int dr4(int n) {   // reverse 5 base-4 digits of 10-bit n
    return ((n & 3) << 8) | (((n >> 2) & 3) << 6) | (((n >> 4) & 3) << 4) |
           (((n >> 6) & 3) << 2) | ((n >> 8) & 3);
}

__device__ inline float2 cmul(float2 a, float2 b) {
    return make_float2(a.x * b.x - a.y * b.y, a.x * b.y + a.y * b.x);
}

__device__ inline void fft1024_r4(float2* X, const float2* tw, int t) {
#pragma unroll
    for (int s = 0; s < 5; ++s) {
        const int L = 1 << (2 * s);
        const int r = t & (L - 1);
        const int base = ((t >> (2 * s)) << (2 * s + 2)) + r;
        float2 A  = X[sw(base)];
        float2 Bv = X[sw(base + L)];
        float2 Cv = X[sw(base + 2 * L)];
        float2 Dv = X[sw(base + 3 * L)];
        if (s != 0) {
            const int step = 1024 >> (2 * s + 2);
            Bv = cmul(Bv, tw[sw(r * step)]);
            Cv = cmul(Cv, tw[sw(2 * r * step)]);
            Dv = cmul(Dv, tw[sw(3 * r * step)]);
        }
        float2 e0 = make_float2(A.x + Cv.x, A.y + Cv.y);
        float2 e1 = make_float2(A.x - Cv.x, A.y - Cv.y);
        float2 o0 = make_float2(Bv.x + Dv.x, Bv.y + Dv.y);
        float2 o1 = make_float2(Bv.x - Dv.x, Bv.y - Dv.y);
        X[sw(base)]         = make_float2(e0.x + o0.x, e0.y + o0.y);
        X[sw(base + L)]     = make_float2(e1.x + o1.y, e1.y - o1.x);
        X[sw(base + 2 * L)] = make_float2(e0.x - o0.x, e0.y - o0.y);
        X[sw(base + 3 * L)] = make_float2(e1.x - o1.y, e1.y + o1.x);
        __syncthreads();
    }
}

__global__ __launch_bounds__(256) void twiddle_init(float2* __restrict__ twg) {
    int k = blockIdx.x * 256 + threadIdx.x;
    if (k < 768) {
        float ang = -6.283185307179586f * (float)k / 1024.0f;
        float s, c;
        sincosf(ang, &s, &c);
        twg[sw(k)] = make_float2(c, s);
    }
}

// ---------------------------------------------------------------------------
// Forward: block handles tokens (2b, 2b+1). QKV is bf16 [tok][3072] = q|k|v.
// ---------------------------------------------------------------------------
__global__ __launch_bounds__(256) void hrr_fft_fwd(const unsigned short* __restrict__ QKV,
                                                   const float2* __restrict__ twg,
                                                   unsigned* __restrict__ Fkv,
                                                   unsigned* __restrict__ Fq) {
    __shared__ __attribute__((aligned(16))) float2 X[1024];
    __shared__ __attribute__((aligned(16))) float2 twL[768];
    const int tid = threadIdx.x;
    const int t0 = blockIdx.x * 2, t1 = t0 + 1;
    for (int i = tid; i < 384; i += 256)
        reinterpret_cast<float4*>(twL)[i] = reinterpret_cast<const float4*>(twg)[i];

#pragma unroll
    for (int which = 0; which < 2; ++which) {
        const int tok = which ? t1 : t0;
        const ushort4* Kr = (const ushort4*)(QKV + (size_t)tok * 3072 + 1024);
        const ushort4* Vr = (const ushort4*)(QKV + (size_t)tok * 3072 + 2048);
        ushort4 k4 = Kr[tid], v4 = Vr[tid];
        X[sw(dr4(4 * tid + 0))] = make_float2(bf2f(k4.x), bf2f(v4.x));
        X[sw(dr4(4 * tid + 1))] = make_float2(bf2f(k4.y), bf2f(v4.y));
        X[sw(dr4(4 * tid + 2))] = make_float2(bf2f(k4.z), bf2f(v4.z));
        X[sw(dr4(4 * tid + 3))] = make_float2(bf2f(k4.w), bf2f(v4.w));
        __syncthreads();
        fft1024_r4(X, twL, tid);
        for (int j = tid; j < NF; j += 256) {
            float2 Zj = X[sw(j)];
            float2 Zm = X[sw((1024 - j) & 1023)];
            float2 Fk = make_float2(0.5f * (Zj.x + Zm.x), 0.5f * (Zj.y - Zm.y));
            float2 Fv = make_float2(0.5f * (Zj.y + Zm.y), 0.5f * (Zm.x - Zj.x));
            float2 p = cmul(Fk, Fv);
            Fkv[(size_t)tok * NF + j] = pkc(p.x, p.y);
        }
        __syncthreads();
    }
    // Q pair
    {
        const ushort4* Q0 = (const ushort4*)(QKV + (size_t)t0 * 3072);
        const ushort4* Q1 = (const ushort4*)(QKV + (size_t)t1 * 3072);
        ushort4 a4 = Q0[tid], b4 = Q1[tid];
        X[sw(dr4(4 * tid + 0))] = make_float2(bf2f(a4.x), bf2f(b4.x));
        X[sw(dr4(4 * tid + 1))] = make_float2(bf2f(a4.y), bf2f(b4.y));
        X[sw(dr4(4 * tid + 2))] = make_float2(bf2f(a4.z), bf2f(b4.z));
        X[sw(dr4(4 * tid + 3))] = make_float2(bf2f(a4.w), bf2f(b4.w));
        __syncthreads();
        fft1024_r4(X, twL, tid);
        for (int j = tid; j < NF; j += 256) {
            float2 Zj = X[sw(j)];
            float2 Zm = X[sw((1024 - j) & 1023)];
            Fq[(size_t)t0 * NF + j] = pkc(0.5f * (Zj.x + Zm.x), 0.5f * (Zj.y - Zm.y));
            Fq[(size_t)t1 * NF + j] = pkc(0.5f * (Zj.y + Zm.y), 0.5f * (Zm.x - Zj.x));
        }
    }
}

// ---------------------------------------------------------------------------
// Chunked causal cumsum (fp32 accumulation over bf16 terms).
// ---------------------------------------------------------------------------
__global__ __launch_bounds__(256) void hrr_chunk_sum(const unsigned* __restrict__ Fkv,
                                                     float2* __restrict__ part) {
    int f = blockIdx.x * 256 + threadIdx.x;
    if (f >= NF) return;
    int ch = blockIdx.y, b = blockIdx.z;
    float sx = 0.f, sy = 0.f;
    size_t base = ((size_t)b * NS + (size_t)ch * CHS) * NF + f;
    for (int i = 0; i < CHS; ++i) {
        float2 t = upc(Fkv[base + (size_t)i * NF]);
        sx += t.x; sy += t.y;
    }
    part[(size_t)(b * NCH + ch) * NF + f] = make_float2(sx, sy);
}

__global__ __launch_bounds__(256) void hrr_scan_apply(unsigned* __restrict__ Fkv,
                                                      const unsigned* __restrict__ Fq,
                                                      const float2* __restrict__ part) {
    int f = blockIdx.x * 256 + threadIdx.x;
    if (f >= NF) return;
    int ch = blockIdx.y, b = blockIdx.z;
    float rx = 0.f, ry = 0.f;
    for (int c2 = 0; c2 < ch; ++c2) {
        float2 p = part[(size_t)(b * NCH + c2) * NF + f];
        rx += p.x; ry += p.y;
    }
    size_t base = ((size_t)b * NS + (size_t)ch * CHS) * NF + f;
    for (int i = 0; i < CHS; ++i) {
        size_t idx = base + (size_t)i * NF;
        float2 kv = upc(Fkv[idx]);
        rx += kv.x; ry += kv.y;
        float2 q = upc(Fq[idx]);
        Fkv[idx] = pkc(rx * q.x + ry * q.y, ry * q.x - rx * q.y);
    }
}

// ---------------------------------------------------------------------------
// Paired irfft of bf16 U; writes vhat bf16.
// ---------------------------------------------------------------------------
__global__ __launch_bounds__(256) void hrr_ifft(const unsigned* __restrict__ U,
                                                const float2* __restrict__ twg,
                                                unsigned short* __restrict__ vhat) {
    __shared__ __attribute__((aligned(16))) float2 X[1024];
    __shared__ __attribute__((aligned(16))) float2 twL[768];
    const int tid = threadIdx.x;
    const int t0 = blockIdx.x * 2, t1 = t0 + 1;
    for (int i = tid; i < 384; i += 256)
        reinterpret_cast<float4*>(twL)[i] = reinterpret_cast<const float4*>(twg)[i];
    const unsigned* U1 = U + (size_t)t0 * NF;
    const unsigned* U2 = U + (size_t)t1 * NF;
#pragma unroll
    for (int c = 0; c < 4; ++c) {
        int j = tid + (c << 8);
        float2 Cv;
        if (j <= 512) {
            float2 u1 = upc(U1[j]), u2 = upc(U2[j]);
            Cv = make_float2(u1.x - u2.y, -u1.y - u2.x);
        } else {
            int m = 1024 - j;
            float2 u1 = upc(U1[m]), u2 = upc(U2[m]);
            Cv = make_float2(u1.x + u2.y, u1.y - u2.x);
        }
        X[sw(dr4(j))] = Cv;
    }
    __syncthreads();
    fft1024_r4(X, twL, tid);
    const float invN = 1.0f / 1024.0f;
#pragma unroll
    for (int c = 0; c < 4; ++c) {
        int n = tid + (c << 8);
        float2 w = X[sw(n)];
        vhat[(size_t)t0 * D_DIM + n] = f2bf(w.x * invN);
        vhat[(size_t)t1 * D_DIM + n] = f2bf(-w.y * invN);
    }
}

// ---------------------------------------------------------------------------
extern "C" void kernel_launch(void* const* d_in, const int* in_sizes, int n_in,
                              void* d_out, int out_size, void* d_ws, size_t ws_size,
                              hipStream_t stream) {
    const float* x  = (const float*)d_in[0];
    const float* Wq = (const float*)d_in[1];
    const float* Wk = (const float*)d_in[2];
    const float* Wv = (const float*)d_in[3];
    const float* Wo = (const float*)d_in[4];
    float* out = (float*)d_out;

    char* ws = (char*)d_ws;
    unsigned short* QKVb = (unsigned short*)(ws + 0);          // 50,331,648 B
    unsigned*       Fkv  = (unsigned*)      (ws + 50331648);   // 16,809,984 B
    unsigned*       Fq   = (unsigned*)      (ws + 67141632);   // 16,809,984 B
    float2*         part = (float2*)        (ws + 83951616);   //    525,312 B
    float2*         twg  = (float2*)        (ws + 84476928);   //      6,144 B
    unsigned short* Wob  = (unsigned short*)(ws + 84483072);   //  2,097,152 B
    unsigned short* Wqkv = (unsigned short*)(ws + 86580224);   //  6,291,456 B
    unsigned short* xb   = (unsigned short*)(ws + 92871680);   // 16,777,216 B
    unsigned short* vhat = (unsigned short*)(ws + 109648896);  // 16,777,216 B (end ~126.4 MB)

    convert_x<<<2048, 256, 0, stream>>>(x, xb, NTOK * D_DIM / 4);
    convert_w<<<dim3(1024, 4), 256, 0, stream>>>(Wq, Wk, Wv, Wo, Wqkv, Wob);
    twiddle_init<<<3, 256, 0, stream>>>(twg);

    // QKV projection with the big-wave-tile kernel: 256x128 blocks
    dim3 gq(NTOK / 256, 3072 / 128);
    gemm_bf16_nt_big<<<gq, 256, 0, stream>>>(xb, Wqkv, QKVb, NTOK, 3072, D_DIM);

    hrr_fft_fwd<<<NTOK / 2, 256, 0, stream>>>(QKVb, twg, Fkv, Fq);

    dim3 gs((NF + 255) / 256, NCH, NB);
    hrr_chunk_sum<<<gs, 256, 0, stream>>>(Fkv, part);
    hrr_scan_apply<<<gs, 256, 0, stream>>>(Fkv, Fq, part);

    hrr_ifft<<<NTOK / 2, 256, 0, stream>>>(Fkv, twg, vhat);

    dim3 go(NTOK / BM, D_DIM / BN);
    gemm_bf16_nt<float><<<go, 256, 0, stream>>>(vhat, Wob, out, NTOK, D_DIM, D_DIM);
}

// Round 9
// 169.882 us; speedup vs baseline: 1.2601x; 1.2601x over previous
//
#include <hip/hip_runtime.h>

#define D_DIM 1024
#define NF 513            // rfft bins = D/2+1
#define NB 4              // batch
#define NS 2048           // sequence
#define NTOK (NB * NS)    // 8192 tokens
#define NCH 32            // cumsum chunks
#define CHS (NS / NCH)    // 64 steps per chunk

typedef __attribute__((ext_vector_type(8))) short short8_t;   // 8 bf16 = 4 VGPRs
typedef __attribute__((ext_vector_type(4))) float f32x4;

__device__ inline unsigned short f2bf(float f) {
    unsigned u = __builtin_bit_cast(unsigned, f);
    u += 0x7FFFu + ((u >> 16) & 1u);   // round-to-nearest-even
    return (unsigned short)(u >> 16);
}
__device__ inline float bf2f(unsigned short h) {
    unsigned u = ((unsigned)h) << 16;
    return __builtin_bit_cast(float, u);
}
__device__ inline unsigned pkc(float re, float im) {   // packed bf16 complex
    return (unsigned)f2bf(re) | ((unsigned)f2bf(im) << 16);
}
__device__ inline float2 upc(unsigned u) {
    return make_float2(bf2f((unsigned short)(u & 0xFFFFu)), bf2f((unsigned short)(u >> 16)));
}

__global__ __launch_bounds__(256) void convert_x(const float* __restrict__ src,
                                                 unsigned short* __restrict__ dst,
                                                 int n4) {
    int i = blockIdx.x * 256 + threadIdx.x;
    int stride = gridDim.x * 256;
    for (; i < n4; i += stride) {
        float4 v = reinterpret_cast<const float4*>(src)[i];
        ushort4 o;
        o.x = f2bf(v.x); o.y = f2bf(v.y); o.z = f2bf(v.z); o.w = f2bf(v.w);
        reinterpret_cast<ushort4*>(dst)[i] = o;
    }
}

// all four weights in one dispatch: gridDim.y selects the weight
__global__ __launch_bounds__(256) void convert_w(const float* __restrict__ Wq,
                                                 const float* __restrict__ Wk,
                                                 const float* __restrict__ Wv,
                                                 const float* __restrict__ Wo,
                                                 unsigned short* __restrict__ Wqkv,
                                                 unsigned short* __restrict__ Wob) {
    int y = blockIdx.y;
    const float* src = (y == 0) ? Wq : (y == 1) ? Wk : (y == 2) ? Wv : Wo;
    unsigned short* dst = (y < 3) ? (Wqkv + (size_t)y * 1048576) : Wob;
    int i = blockIdx.x * 256 + threadIdx.x;
    float4 v = reinterpret_cast<const float4*>(src)[i];
    ushort4 o;
    o.x = f2bf(v.x); o.y = f2bf(v.y); o.z = f2bf(v.z); o.w = f2bf(v.w);
    reinterpret_cast<ushort4*>(dst)[i] = o;
}

__device__ inline void gload_lds16(const void* g, void* l) {
    __builtin_amdgcn_global_load_lds(
        (const __attribute__((address_space(1))) void*)g,
        (__attribute__((address_space(3))) void*)l,
        16, 0, 0);
}

// ---------------------------------------------------------------------------
// bf16 MFMA GEMM: C[M,N] = A[M,K] * B[N,K]^T.  128x128 tile, BK=64.
// 4 waves of 64x64 (acc=64 regs -> 3 waves/SIMD occupancy preserved).
// 2-buffer LDS (64 KB), counted vmcnt(8) steady / 0 tail (8 loads/thread/tile).
// Half the barrier rounds of BK=32 (NT=16), 2x MFMA per round.
// Swizzle (BK=64, 128B row stride): logical slot s=kk*4+(lane>>4), physical
// slot = s ^ (row&7); staging source col = ((t&7)^((t>>3)&7))*8, LDS dest
// linear.  Same involution both sides; bank-uniform (verified by hand).
// ---------------------------------------------------------------------------
template <typename OutT>
__global__ __launch_bounds__(256) void gemm_bf16_bk64(const unsigned short* __restrict__ A,
                                                      const unsigned short* __restrict__ B,
                                                      OutT* __restrict__ C,
                                                      int M, int N, int K) {
    __shared__ __attribute__((aligned(16))) unsigned short ldsA[2 * 128 * 64];  // 32 KiB
    __shared__ __attribute__((aligned(16))) unsigned short ldsB[2 * 128 * 64];  // 32 KiB
    const int tid  = threadIdx.x;
    const int wave = tid >> 6;
    const int lane = tid & 63;
    const int l15  = lane & 15;
    const int q4   = (lane >> 4) & 3;
    const int h7   = l15 & 7;
    const int p0   = ((q4)     ^ h7) << 3;   // elem col offset, kk=0 (logical slots 0..3)
    const int p1   = ((4 + q4) ^ h7) << 3;   // kk=1 (logical slots 4..7)
    const int wm   = (wave >> 1) * 64;
    const int wn   = (wave & 1) * 64;
    const int bm   = blockIdx.x * 128;
    const int bn   = blockIdx.y * 128;
    const int srow = tid >> 3;                              // 0..31
    const int scol = (((tid & 7) ^ ((tid >> 3) & 7)) << 3); // inverse-swizzled global col
    const int NT   = K >> 6;

    const unsigned short* Asrc = A + (size_t)(bm + srow) * K + scol;
    const unsigned short* Bsrc = B + (size_t)(bn + srow) * K + scol;
    const size_t cstep = (size_t)32 * K;

    f32x4 acc[4][4];
#pragma unroll
    for (int i = 0; i < 4; ++i)
#pragma unroll
        for (int j = 0; j < 4; ++j)
            acc[i][j] = (f32x4){0.f, 0.f, 0.f, 0.f};

    // STAGE(tile t -> buffer b): 8 global_load_lds per thread (A:4, B:4).
    // Dest is linear: thread t covers 16B at c*4096 + t*16 bytes per tensor.
    auto STAGE = [&](int t, int b) {
        const int k0 = t << 6;
        unsigned short* la = &ldsA[b * 8192 + tid * 8];
        unsigned short* lb = &ldsB[b * 8192 + tid * 8];
        gload_lds16(Asrc + k0,             la);
        gload_lds16(Asrc + cstep + k0,     la + 2048);
        gload_lds16(Asrc + 2 * cstep + k0, la + 4096);
        gload_lds16(Asrc + 3 * cstep + k0, la + 6144);
        gload_lds16(Bsrc + k0,             lb);
        gload_lds16(Bsrc + cstep + k0,     lb + 2048);
        gload_lds16(Bsrc + 2 * cstep + k0, lb + 4096);
        gload_lds16(Bsrc + 3 * cstep + k0, lb + 6144);
    };

    STAGE(0, 0);

    for (int j = 0; j < NT; ++j) {
        const int buf = j & 1;
        if (j + 1 < NT) {
            STAGE(j + 1, buf ^ 1);
            asm volatile("s_waitcnt vmcnt(8)" ::: "memory");   // tile j landed; j+1 in flight
        } else {
            asm volatile("s_waitcnt vmcnt(0)" ::: "memory");
        }
        __builtin_amdgcn_s_barrier();
        asm volatile("" ::: "memory");

        const unsigned short* la = &ldsA[buf * 8192];
        const unsigned short* lb = &ldsB[buf * 8192];

        // --- kk = 0 ---
        {
            short8_t af[4], bfv[4];
#pragma unroll
            for (int mi = 0; mi < 4; ++mi)
                af[mi] = *reinterpret_cast<const short8_t*>(&la[(wm + mi * 16 + l15) * 64 + p0]);
#pragma unroll
            for (int ni = 0; ni < 4; ++ni)
                bfv[ni] = *reinterpret_cast<const short8_t*>(&lb[(wn + ni * 16 + l15) * 64 + p0]);
            __builtin_amdgcn_s_setprio(1);
#pragma unroll
            for (int mi = 0; mi < 4; ++mi)
#pragma unroll
                for (int ni = 0; ni < 4; ++ni)
                    acc[mi][ni] = __builtin_amdgcn_mfma_f32_16x16x32_bf16(af[mi], bfv[ni], acc[mi][ni], 0, 0, 0);
            __builtin_amdgcn_s_setprio(0);
        }
        // --- kk = 1 ---
        {
            short8_t af[4], bfv[4];
#pragma unroll
            for (int mi = 0; mi < 4; ++mi)
                af[mi] = *reinterpret_cast<const short8_t*>(&la[(wm + mi * 16 + l15) * 64 + p1]);
#pragma unroll
            for (int ni = 0; ni < 4; ++ni)
                bfv[ni] = *reinterpret_cast<const short8_t*>(&lb[(wn + ni * 16 + l15) * 64 + p1]);
            __builtin_amdgcn_s_setprio(1);
#pragma unroll
            for (int mi = 0; mi < 4; ++mi)
#pragma unroll
                for (int ni = 0; ni < 4; ++ni)
                    acc[mi][ni] = __builtin_amdgcn_mfma_f32_16x16x32_bf16(af[mi], bfv[ni], acc[mi][ni], 0, 0, 0);
            __builtin_amdgcn_s_setprio(0);
        }

        __builtin_amdgcn_s_barrier();   // all reads done before next STAGE overwrite
        asm volatile("" ::: "memory");
    }

#pragma unroll
    for (int mi = 0; mi < 4; ++mi) {
        int rbase = bm + wm + mi * 16 + (lane >> 4) * 4;
#pragma unroll
        for (int ni = 0; ni < 4; ++ni) {
            int col = bn + wn + ni * 16 + l15;
#pragma unroll
            for (int j = 0; j < 4; ++j) {
                float v = acc[mi][ni][j];
                if constexpr (sizeof(OutT) == 4)
                    C[(size_t)(rbase + j) * N + col] = v;
                else
                    C[(size_t)(rbase + j) * N + col] = f2bf(v);
            }
        }
    }
}

// ---------------------------------------------------------------------------
// Radix-4 1024-pt complex FFT in LDS, float2 elements, XOR bank swizzle.
// ---------------------------------------------------------------------------
__device__ inline int sw(int i) { return i ^ ((i >> 4) & 15); }

__device__ inline int dr4(int n) {   // reverse 5 base-4 digits of 10-bit n
    return ((n & 3) << 8) | (((n >> 2) & 3) << 6) | (((n >> 4) & 3) << 4) |
           (((n >> 6) & 3) << 2) | ((n >> 8) & 3);
}

__device__ inline float2 cmul(float2 a, float2 b) {
    return make_float2(a.x * b.x - a.y * b.y, a.x * b.y + a.y * b.x);
}

__device__ inline void fft1024_r4(float2* X, const float2* tw, int t) {
#pragma unroll
    for (int s = 0; s < 5; ++s) {
        const int L = 1 << (2 * s);
        const int r = t & (L - 1);
        const int base = ((t >> (2 * s)) << (2 * s + 2)) + r;
        float2 A  = X[sw(base)];
        float2 Bv = X[sw(base + L)];
        float2 Cv = X[sw(base + 2 * L)];
        float2 Dv = X[sw(base + 3 * L)];
        if (s != 0) {
            const int step = 1024 >> (2 * s + 2);
            Bv = cmul(Bv, tw[sw(r * step)]);
            Cv = cmul(Cv, tw[sw(2 * r * step)]);
            Dv = cmul(Dv, tw[sw(3 * r * step)]);
        }
        float2 e0 = make_float2(A.x + Cv.x, A.y + Cv.y);
        float2 e1 = make_float2(A.x - Cv.x, A.y - Cv.y);
        float2 o0 = make_float2(Bv.x + Dv.x, Bv.y + Dv.y);
        float2 o1 = make_float2(Bv.x - Dv.x, Bv.y - Dv.y);
        X[sw(base)]         = make_float2(e0.x + o0.x, e0.y + o0.y);
        X[sw(base + L)]     = make_float2(e1.x + o1.y, e1.y - o1.x);
        X[sw(base + 2 * L)] = make_float2(e0.x - o0.x, e0.y - o0.y);
        X[sw(base + 3 * L)] = make_float2(e1.x - o1.y, e1.y + o1.x);
        __syncthreads();
    }
}

__global__ __launch_bounds__(256) void twiddle_init(float2* __restrict__ twg) {
    int k = blockIdx.x * 256 + threadIdx.x;
    if (k < 768) {
        float ang = -6.283185307179586f * (float)k / 1024.0f;
        float s, c;
        sincosf(ang, &s, &c);
        twg[sw(k)] = make_float2(c, s);
    }
}

// ---------------------------------------------------------------------------
// Forward: block handles tokens (2b, 2b+1). QKV is bf16 [tok][3072] = q|k|v.
// ---------------------------------------------------------------------------
__global__ __launch_bounds__(256) void hrr_fft_fwd(const unsigned short* __restrict__ QKV,
                                                   const float2* __restrict__ twg,
                                                   unsigned* __restrict__ Fkv,
                                                   unsigned* __restrict__ Fq) {
    __shared__ __attribute__((aligned(16))) float2 X[1024];
    __shared__ __attribute__((aligned(16))) float2 twL[768];
    const int tid = threadIdx.x;
    const int t0 = blockIdx.x * 2, t1 = t0 + 1;
    for (int i = tid; i < 384; i += 256)
        reinterpret_cast<float4*>(twL)[i] = reinterpret_cast<const float4*>(twg)[i];

#pragma unroll
    for (int which = 0; which < 2; ++which) {
        const int tok = which ? t1 : t0;
        const ushort4* Kr = (const ushort4*)(QKV + (size_t)tok * 3072 + 1024);
        const ushort4* Vr = (const ushort4*)(QKV + (size_t)tok * 3072 + 2048);
        ushort4 k4 = Kr[tid], v4 = Vr[tid];
        X[sw(dr4(4 * tid + 0))] = make_float2(bf2f(k4.x), bf2f(v4.x));
        X[sw(dr4(4 * tid + 1))] = make_float2(bf2f(k4.y), bf2f(v4.y));
        X[sw(dr4(4 * tid + 2))] = make_float2(bf2f(k4.z), bf2f(v4.z));
        X[sw(dr4(4 * tid + 3))] = make_float2(bf2f(k4.w), bf2f(v4.w));
        __syncthreads();
        fft1024_r4(X, twL, tid);
        for (int j = tid; j < NF; j += 256) {
            float2 Zj = X[sw(j)];
            float2 Zm = X[sw((1024 - j) & 1023)];
            float2 Fk = make_float2(0.5f * (Zj.x + Zm.x), 0.5f * (Zj.y - Zm.y));
            float2 Fv = make_float2(0.5f * (Zj.y + Zm.y), 0.5f * (Zm.x - Zj.x));
            float2 p = cmul(Fk, Fv);
            Fkv[(size_t)tok * NF + j] = pkc(p.x, p.y);
        }
        __syncthreads();
    }
    // Q pair
    {
        const ushort4* Q0 = (const ushort4*)(QKV + (size_t)t0 * 3072);
        const ushort4* Q1 = (const ushort4*)(QKV + (size_t)t1 * 3072);
        ushort4 a4 = Q0[tid], b4 = Q1[tid];
        X[sw(dr4(4 * tid + 0))] = make_float2(bf2f(a4.x), bf2f(b4.x));
        X[sw(dr4(4 * tid + 1))] = make_float2(bf2f(a4.y), bf2f(b4.y));
        X[sw(dr4(4 * tid + 2))] = make_float2(bf2f(a4.z), bf2f(b4.z));
        X[sw(dr4(4 * tid + 3))] = make_float2(bf2f(a4.w), bf2f(b4.w));
        __syncthreads();
        fft1024_r4(X, twL, tid);
        for (int j = tid; j < NF; j += 256) {
            float2 Zj = X[sw(j)];
            float2 Zm = X[sw((1024 - j) & 1023)];
            Fq[(size_t)t0 * NF + j] = pkc(0.5f * (Zj.x + Zm.x), 0.5f * (Zj.y - Zm.y));
            Fq[(size_t)t1 * NF + j] = pkc(0.5f * (Zj.y + Zm.y), 0.5f * (Zm.x - Zj.x));
        }
    }
}

// ---------------------------------------------------------------------------
// Chunked causal cumsum (fp32 accumulation over bf16 terms).
// ---------------------------------------------------------------------------
__global__ __launch_bounds__(256) void hrr_chunk_sum(const unsigned* __restrict__ Fkv,
                                                     float2* __restrict__ part) {
    int f = blockIdx.x * 256 + threadIdx.x;
    if (f >= NF) return;
    int ch = blockIdx.y, b = blockIdx.z;
    float sx = 0.f, sy = 0.f;
    size_t base = ((size_t)b * NS + (size_t)ch * CHS) * NF + f;
    for (int i = 0; i < CHS; ++i) {
        float2 t = upc(Fkv[base + (size_t)i * NF]);
        sx += t.x; sy += t.y;
    }
    part[(size_t)(b * NCH + ch) * NF + f] = make_float2(sx, sy);
}

__global__ __launch_bounds__(256) void hrr_scan_apply(unsigned* __restrict__ Fkv,
                                                      const unsigned* __restrict__ Fq,
                                                      const float2* __restrict__ part) {
    int f = blockIdx.x * 256 + threadIdx.x;
    if (f >= NF) return;
    int ch = blockIdx.y, b = blockIdx.z;
    float rx = 0.f, ry = 0.f;
    for (int c2 = 0; c2 < ch; ++c2) {
        float2 p = part[(size_t)(b * NCH + c2) * NF + f];
        rx += p.x; ry += p.y;
    }
    size_t base = ((size_t)b * NS + (size_t)ch * CHS) * NF + f;
    for (int i = 0; i < CHS; ++i) {
        size_t idx = base + (size_t)i * NF;
        float2 kv = upc(Fkv[idx]);
        rx += kv.x; ry += kv.y;
        float2 q = upc(Fq[idx]);
        Fkv[idx] = pkc(rx * q.x + ry * q.y, ry * q.x - rx * q.y);
    }
}

// ---------------------------------------------------------------------------
// Paired irfft of bf16 U; writes vhat bf16.
// ---------------------------------------------------------------------------
__global__ __launch_bounds__(256) void hrr_ifft(const unsigned* __restrict__ U,
                                                const float2* __restrict__ twg,
                                                unsigned short* __restrict__ vhat) {
    __shared__ __attribute__((aligned(16))) float2 X[1024];
    __shared__ __attribute__((aligned(16))) float2 twL[768];
    const int tid = threadIdx.x;
    const int t0 = blockIdx.x * 2, t1 = t0 + 1;
    for (int i = tid; i < 384; i += 256)
        reinterpret_cast<float4*>(twL)[i] = reinterpret_cast<const float4*>(twg)[i];
    const unsigned* U1 = U + (size_t)t0 * NF;
    const unsigned* U2 = U + (size_t)t1 * NF;
#pragma unroll
    for (int c = 0; c < 4; ++c) {
        int j = tid + (c << 8);
        float2 Cv;
        if (j <= 512) {
            float2 u1 = upc(U1[j]), u2 = upc(U2[j]);
            Cv = make_float2(u1.x - u2.y, -u1.y - u2.x);
        } else {
            int m = 1024 - j;
            float2 u1 = upc(U1[m]), u2 = upc(U2[m]);
            Cv = make_float2(u1.x + u2.y, u1.y - u2.x);
        }
        X[sw(dr4(j))] = Cv;
    }
    __syncthreads();
    fft1024_r4(X, twL, tid);
    const float invN = 1.0f / 1024.0f;
#pragma unroll
    for (int c = 0; c < 4; ++c) {
        int n = tid + (c << 8);
        float2 w = X[sw(n)];
        vhat[(size_t)t0 * D_DIM + n] = f2bf(w.x * invN);
        vhat[(size_t)t1 * D_DIM + n] = f2bf(-w.y * invN);
    }
}

// ---------------------------------------------------------------------------
extern "C" void kernel_launch(void* const* d_in, const int* in_sizes, int n_in,
                              void* d_out, int out_size, void* d_ws, size_t ws_size,
                              hipStream_t stream) {
    const float* x  = (const float*)d_in[0];
    const float* Wq = (const float*)d_in[1];
    const float* Wk = (const float*)d_in[2];
    const float* Wv = (const float*)d_in[3];
    const float* Wo = (const float*)d_in[4];
    float* out = (float*)d_out;

    char* ws = (char*)d_ws;
    unsigned short* QKVb = (unsigned short*)(ws + 0);          // 50,331,648 B
    unsigned*       Fkv  = (unsigned*)      (ws + 50331648);   // 16,809,984 B
    unsigned*       Fq   = (unsigned*)      (ws + 67141632);   // 16,809,984 B
    float2*         part = (float2*)        (ws + 83951616);   //    525,312 B
    float2*         twg  = (float2*)        (ws + 84476928);   //      6,144 B
    unsigned short* Wob  = (unsigned short*)(ws + 84483072);   //  2,097,152 B
    unsigned short* Wqkv = (unsigned short*)(ws + 86580224);   //  6,291,456 B
    unsigned short* xb   = (unsigned short*)(ws + 92871680);   // 16,777,216 B
    unsigned short* vhat = (unsigned short*)(ws + 109648896);  // 16,777,216 B (end ~126.4 MB)

    convert_x<<<2048, 256, 0, stream>>>(x, xb, NTOK * D_DIM / 4);
    convert_w<<<dim3(1024, 4), 256, 0, stream>>>(Wq, Wk, Wv, Wo, Wqkv, Wob);
    twiddle_init<<<3, 256, 0, stream>>>(twg);

    dim3 gq(NTOK / 128, 3072 / 128);
    gemm_bf16_bk64<unsigned short><<<gq, 256, 0, stream>>>(xb, Wqkv, QKVb, NTOK, 3072, D_DIM);

    hrr_fft_fwd<<<NTOK / 2, 256, 0, stream>>>(QKVb, twg, Fkv, Fq);

    dim3 gs((NF + 255) / 256, NCH, NB);
    hrr_chunk_sum<<<gs, 256, 0, stream>>>(Fkv, part);
    hrr_scan_apply<<<gs, 256, 0, stream>>>(Fkv, Fq, part);

    hrr_ifft<<<NTOK / 2, 256, 0, stream>>>(Fkv, twg, vhat);

    dim3 go(NTOK / 128, D_DIM / 128);
    gemm_bf16_bk64<float><<<go, 256, 0, stream>>>(vhat, Wob, out, NTOK, D_DIM, D_DIM);
}